// Round 1
// baseline (491.363 us; speedup 1.0000x reference)
//
#include <hip/hip_runtime.h>
#include <cstdint>
#include <cstddef>

#define BDIM 8192
#define DDIM 512

typedef __bf16 bf16x8 __attribute__((ext_vector_type(8)));
typedef float f32x4 __attribute__((ext_vector_type(4)));

__device__ inline unsigned short f32_to_bf16(float f) {
    unsigned int u = __float_as_uint(f);
    u += 0x7FFF + ((u >> 16) & 1);   // RNE
    return (unsigned short)(u >> 16);
}

// One block per row (128 threads, 2 waves). Row-normalize fp32 -> bf16.
__global__ __launch_bounds__(128) void normalize_kernel(
    const float* __restrict__ a, const float* __restrict__ b,
    unsigned short* __restrict__ an, unsigned short* __restrict__ bn)
{
    int row = blockIdx.x;
    const float* src;
    unsigned short* dst;
    if (row < BDIM) {
        src = a + (size_t)row * DDIM;
        dst = an + (size_t)row * DDIM;
    } else {
        src = b + (size_t)(row - BDIM) * DDIM;
        dst = bn + (size_t)(row - BDIM) * DDIM;
    }
    int t = threadIdx.x;
    float4 v = reinterpret_cast<const float4*>(src)[t];
    float ss = v.x * v.x + v.y * v.y + v.z * v.z + v.w * v.w;
#pragma unroll
    for (int m = 1; m < 64; m <<= 1) ss += __shfl_xor(ss, m);
    __shared__ float red[2];
    if ((t & 63) == 0) red[t >> 6] = ss;
    __syncthreads();
    float inv = 1.0f / fmaxf(sqrtf(red[0] + red[1]), 1e-8f);  // torch eps clamp
    ushort4 o;
    o.x = f32_to_bf16(v.x * inv);
    o.y = f32_to_bf16(v.y * inv);
    o.z = f32_to_bf16(v.z * inv);
    o.w = f32_to_bf16(v.w * inv);
    reinterpret_cast<ushort4*>(dst)[t] = o;
}

// 128x128 tile, BK=64, 4 waves in 2x2, each wave 64x64 via 4x4 MFMA 16x16x32.
// LDS chunk swizzle: 16B chunk c of row r stored at slot c^(r&7) -> ds_read_b128
// fragment loads are 2-way (free); global_load_lds needs base+lane*16 so the
// swizzle is applied by permuting the *global* chunk each LDS slot receives.
__global__ __launch_bounds__(256, 3) void gemm_fused_kernel(
    const unsigned short* __restrict__ an, const unsigned short* __restrict__ bn,
    const int* __restrict__ labels, float* __restrict__ cos_out,
    float* __restrict__ num, float* __restrict__ den)
{
    __shared__ __align__(16) unsigned short sA[128 * 64];
    __shared__ __align__(16) unsigned short sB[128 * 64];

    const int t = threadIdx.x;
    const int wid = t >> 6;
    const int lane = t & 63;
    const int quad = lane >> 4;
    const int lr = lane & 15;
    const int bm = blockIdx.y;
    const int bnb = blockIdx.x;
    const int wm = wid >> 1;
    const int wn = wid & 1;

    f32x4 acc[4][4] = {};

    const char* aBase = (const char*)an;
    const char* bBase = (const char*)bn;
    char* sAB = (char*)sA;
    char* sBB = (char*)sB;

    // staging: thread t, call c moves 16B to LDS chunk li = c*256+t
    // (LDS byte = li*16 = c*4096 + wid*1024 + lane*16); that slot holds
    // global chunk (li&7)^(r&7) of row r = li>>3.
    size_t gOffA[4], gOffB[4];
#pragma unroll
    for (int c = 0; c < 4; ++c) {
        int li = c * 256 + t;
        int r = li >> 3;
        int cch = (li & 7) ^ (r & 7);
        gOffA[c] = (size_t)(bm * 128 + r) * (DDIM * 2) + cch * 16;
        gOffB[c] = (size_t)(bnb * 128 + r) * (DDIM * 2) + cch * 16;
    }

    for (int k0 = 0; k0 < DDIM; k0 += 64) {
#pragma unroll
        for (int c = 0; c < 4; ++c) {
            __builtin_amdgcn_global_load_lds(
                (const __attribute__((address_space(1))) void*)(aBase + gOffA[c] + k0 * 2),
                (__attribute__((address_space(3))) void*)(sAB + c * 4096 + wid * 1024),
                16, 0, 0);
            __builtin_amdgcn_global_load_lds(
                (const __attribute__((address_space(1))) void*)(bBase + gOffB[c] + k0 * 2),
                (__attribute__((address_space(3))) void*)(sBB + c * 4096 + wid * 1024),
                16, 0, 0);
        }
        __syncthreads();
#pragma unroll
        for (int kk = 0; kk < 2; ++kk) {
            bf16x8 af[4], bfr[4];
#pragma unroll
            for (int mi = 0; mi < 4; ++mi) {
                int r = wm * 64 + mi * 16 + lr;
                int cch = (kk * 4 + quad) ^ (r & 7);
                af[mi] = *(const bf16x8*)(sAB + r * 128 + cch * 16);
            }
#pragma unroll
            for (int ni = 0; ni < 4; ++ni) {
                int r = wn * 64 + ni * 16 + lr;
                int cch = (kk * 4 + quad) ^ (r & 7);
                bfr[ni] = *(const bf16x8*)(sBB + r * 128 + cch * 16);
            }
#pragma unroll
            for (int mi = 0; mi < 4; ++mi)
#pragma unroll
                for (int ni = 0; ni < 4; ++ni)
                    acc[mi][ni] = __builtin_amdgcn_mfma_f32_16x16x32_bf16(
                        af[mi], bfr[ni], acc[mi][ni], 0, 0, 0);
        }
        __syncthreads();
    }

    // Epilogue: store cos tile + fused masked/unmasked exp row-sums.
    // C/D layout (m89/m91): col = lane&15, row = quad*4 + reg.
    const float INV_T = 1.0f / 0.07f;
    const int col0 = bnb * 128 + wn * 64 + lr;
    int lab_c[4];
#pragma unroll
    for (int ni = 0; ni < 4; ++ni) lab_c[ni] = labels[col0 + ni * 16];

#pragma unroll
    for (int mi = 0; mi < 4; ++mi) {
        int rbase = bm * 128 + wm * 64 + mi * 16 + quad * 4;
#pragma unroll
        for (int r = 0; r < 4; ++r) {
            int row = rbase + r;
            int lab_r = labels[row];
            float dsum = 0.0f, nsum = 0.0f;
#pragma unroll
            for (int ni = 0; ni < 4; ++ni) {
                float cv = acc[mi][ni][r];
                cos_out[(size_t)row * BDIM + col0 + ni * 16] = cv;
                float e = __expf(cv * INV_T);
                dsum += e;
                nsum += (lab_c[ni] == lab_r) ? e : 0.0f;
            }
            // reduce across the 16 lanes sharing this row
#pragma unroll
            for (int m = 1; m < 16; m <<= 1) {
                dsum += __shfl_xor(dsum, m);
                nsum += __shfl_xor(nsum, m);
            }
            if (lr == 0) {
                atomicAdd(&den[row], dsum);
                atomicAdd(&num[row], nsum);
            }
        }
    }
}

__global__ __launch_bounds__(256) void loss_kernel(
    const float* __restrict__ num, const float* __restrict__ den,
    float* __restrict__ out)
{
    int t = threadIdx.x;
    float s = 0.0f;
    for (int i = t; i < BDIM; i += 256) s += logf(num[i] / den[i]);
#pragma unroll
    for (int m = 1; m < 64; m <<= 1) s += __shfl_xor(s, m);
    __shared__ float red[4];
    if ((t & 63) == 0) red[t >> 6] = s;
    __syncthreads();
    if (t == 0) out[0] = -(red[0] + red[1] + red[2] + red[3]) / (float)BDIM;
}

extern "C" void kernel_launch(void* const* d_in, const int* in_sizes, int n_in,
                              void* d_out, int out_size, void* d_ws, size_t ws_size,
                              hipStream_t stream)
{
    const int* labels = (const int*)d_in[0];
    const float* fa = (const float*)d_in[1];
    const float* fb = (const float*)d_in[2];
    float* out = (float*)d_out;

    // ws: a_n bf16 (8 MB) | b_n bf16 (8 MB) | num f32 (32 KB) | den f32 (32 KB)
    unsigned short* an = (unsigned short*)d_ws;
    unsigned short* bn = an + (size_t)BDIM * DDIM;
    float* num = (float*)(bn + (size_t)BDIM * DDIM);
    float* den = num + BDIM;

    hipMemsetAsync(num, 0, 2 * BDIM * sizeof(float), stream);  // ws is poisoned each call
    normalize_kernel<<<2 * BDIM, 128, 0, stream>>>(fa, fb, an, bn);
    dim3 grid(64, 64);
    gemm_fused_kernel<<<grid, 256, 0, stream>>>(an, bn, labels, out + 1, num, den);
    loss_kernel<<<1, 256, 0, stream>>>(num, den, out);
}

// Round 2
// 388.504 us; speedup vs baseline: 1.2648x; 1.2648x over previous
//
#include <hip/hip_runtime.h>
#include <cstdint>
#include <cstddef>

#define BDIM 8192
#define DDIM 512

typedef __bf16 bf16x8 __attribute__((ext_vector_type(8)));
typedef float f32x4 __attribute__((ext_vector_type(4)));

__device__ inline unsigned short f32_to_bf16(float f) {
    unsigned int u = __float_as_uint(f);
    u += 0x7FFF + ((u >> 16) & 1);   // RNE
    return (unsigned short)(u >> 16);
}

// One WAVE per row (no LDS, no barriers). 256 threads = 4 rows/block.
// Row-normalize fp32 -> bf16 with torch eps clamp.
__global__ __launch_bounds__(256) void normalize_kernel(
    const float* __restrict__ a, const float* __restrict__ b,
    unsigned short* __restrict__ an, unsigned short* __restrict__ bn)
{
    const int lane = threadIdx.x & 63;
    const int row = blockIdx.x * 4 + (threadIdx.x >> 6);
    const float* src;
    unsigned short* dst;
    if (row < BDIM) {
        src = a + (size_t)row * DDIM;
        dst = an + (size_t)row * DDIM;
    } else {
        src = b + (size_t)(row - BDIM) * DDIM;
        dst = bn + (size_t)(row - BDIM) * DDIM;
    }
    const float4* s4 = (const float4*)src;
    float4 v0 = s4[lane];
    float4 v1 = s4[lane + 64];
    float ss = v0.x * v0.x + v0.y * v0.y + v0.z * v0.z + v0.w * v0.w
             + v1.x * v1.x + v1.y * v1.y + v1.z * v1.z + v1.w * v1.w;
#pragma unroll
    for (int m = 1; m < 64; m <<= 1) ss += __shfl_xor(ss, m);
    float inv = 1.0f / fmaxf(sqrtf(ss), 1e-8f);
    ushort4 o0, o1;
    o0.x = f32_to_bf16(v0.x * inv); o0.y = f32_to_bf16(v0.y * inv);
    o0.z = f32_to_bf16(v0.z * inv); o0.w = f32_to_bf16(v0.w * inv);
    o1.x = f32_to_bf16(v1.x * inv); o1.y = f32_to_bf16(v1.y * inv);
    o1.z = f32_to_bf16(v1.z * inv); o1.w = f32_to_bf16(v1.w * inv);
    ushort4* d4 = (ushort4*)dst;
    d4[lane] = o0;
    d4[lane + 64] = o1;
}

// Block tile 128(M) x 256(N), BK=64. 4 waves in 2(M) x 2(N); each wave 64x128
// via 4x8 MFMA 16x16x32 bf16. LDS chunk swizzle: 16B chunk c of row r lives at
// slot c^(r&7) -> ds_read_b128 fragment loads conflict-free; global_load_lds
// needs base+lane*16 so the swizzle permutes which GLOBAL chunk each LDS slot
// receives.
__global__ __launch_bounds__(256, 2) void gemm_fused_kernel(
    const unsigned short* __restrict__ an, const unsigned short* __restrict__ bn,
    const int* __restrict__ labels, float* __restrict__ cos_out,
    float* __restrict__ num, float* __restrict__ den)
{
    __shared__ __align__(16) unsigned short sA[128 * 64];
    __shared__ __align__(16) unsigned short sB[256 * 64];

    const int t = threadIdx.x;
    const int wid = t >> 6;
    const int lane = t & 63;
    const int quad = lane >> 4;
    const int lr = lane & 15;
    const int bm = blockIdx.y;   // 64 M-blocks
    const int bnb = blockIdx.x;  // 32 N-blocks
    const int wm = wid >> 1;
    const int wn = wid & 1;

    f32x4 acc[4][8] = {};

    const char* aBase = (const char*)an;
    const char* bBase = (const char*)bn;
    char* sAB = (char*)sA;
    char* sBB = (char*)sB;

    // staging: thread t, call c moves 16B to LDS chunk li = c*256+t; that slot
    // holds global chunk (li&7)^(r&7) of row r = li>>3.
    unsigned gOffA[4], gOffB[8];
#pragma unroll
    for (int c = 0; c < 4; ++c) {
        int li = c * 256 + t;
        int r = li >> 3;
        int cch = (li & 7) ^ (r & 7);
        gOffA[c] = (unsigned)((bm * 128 + r) * (DDIM * 2) + cch * 16);
    }
#pragma unroll
    for (int c = 0; c < 8; ++c) {
        int li = c * 256 + t;
        int r = li >> 3;
        int cch = (li & 7) ^ (r & 7);
        gOffB[c] = (unsigned)((bnb * 256 + r) * (DDIM * 2) + cch * 16);
    }

    for (int k0 = 0; k0 < DDIM; k0 += 64) {
#pragma unroll
        for (int c = 0; c < 4; ++c)
            __builtin_amdgcn_global_load_lds(
                (const __attribute__((address_space(1))) void*)(aBase + gOffA[c] + k0 * 2),
                (__attribute__((address_space(3))) void*)(sAB + c * 4096 + wid * 1024),
                16, 0, 0);
#pragma unroll
        for (int c = 0; c < 8; ++c)
            __builtin_amdgcn_global_load_lds(
                (const __attribute__((address_space(1))) void*)(bBase + gOffB[c] + k0 * 2),
                (__attribute__((address_space(3))) void*)(sBB + c * 4096 + wid * 1024),
                16, 0, 0);
        __syncthreads();
#pragma unroll
        for (int kk = 0; kk < 2; ++kk) {
            bf16x8 af[4], bfr[8];
#pragma unroll
            for (int mi = 0; mi < 4; ++mi) {
                int r = wm * 64 + mi * 16 + lr;
                int cch = (kk * 4 + quad) ^ (r & 7);
                af[mi] = *(const bf16x8*)(sAB + r * 128 + cch * 16);
            }
#pragma unroll
            for (int ni = 0; ni < 8; ++ni) {
                int r = wn * 128 + ni * 16 + lr;
                int cch = (kk * 4 + quad) ^ (r & 7);
                bfr[ni] = *(const bf16x8*)(sBB + r * 128 + cch * 16);
            }
#pragma unroll
            for (int mi = 0; mi < 4; ++mi)
#pragma unroll
                for (int ni = 0; ni < 8; ++ni)
                    acc[mi][ni] = __builtin_amdgcn_mfma_f32_16x16x32_bf16(
                        af[mi], bfr[ni], acc[mi][ni], 0, 0, 0);
        }
        __syncthreads();
    }

    // Epilogue: store cos tile + fused masked/unmasked exp row-sums.
    // C/D layout (m89/m91): col = lane&15, row = quad*4 + reg.
    const float INV_T = 1.0f / 0.07f;
    const int col0 = bnb * 256 + wn * 128 + lr;
    int lab_c[8];
#pragma unroll
    for (int ni = 0; ni < 8; ++ni) lab_c[ni] = labels[col0 + ni * 16];

#pragma unroll
    for (int mi = 0; mi < 4; ++mi) {
        int rbase = bm * 128 + wm * 64 + mi * 16 + quad * 4;
#pragma unroll
        for (int r = 0; r < 4; ++r) {
            int row = rbase + r;
            int lab_r = labels[row];
            float dsum = 0.0f, nsum = 0.0f;
#pragma unroll
            for (int ni = 0; ni < 8; ++ni) {
                float cv = acc[mi][ni][r];
                cos_out[(size_t)row * BDIM + col0 + ni * 16] = cv;
                float e = __expf(cv * INV_T);
                dsum += e;
                nsum += (lab_c[ni] == lab_r) ? e : 0.0f;
            }
            // reduce across the 16 lanes sharing this row
#pragma unroll
            for (int m = 1; m < 16; m <<= 1) {
                dsum += __shfl_xor(dsum, m);
                nsum += __shfl_xor(nsum, m);
            }
            if (lr == 0) {
                atomicAdd(&den[row], dsum);
                atomicAdd(&num[row], nsum);
            }
        }
    }
}

__global__ __launch_bounds__(1024) void loss_kernel(
    const float* __restrict__ num, const float* __restrict__ den,
    float* __restrict__ out)
{
    int t = threadIdx.x;
    float s = 0.0f;
#pragma unroll
    for (int i = 0; i < 8; ++i) {
        int idx = t + i * 1024;
        s += __logf(num[idx] / den[idx]);
    }
#pragma unroll
    for (int m = 1; m < 64; m <<= 1) s += __shfl_xor(s, m);
    __shared__ float red[16];
    if ((t & 63) == 0) red[t >> 6] = s;
    __syncthreads();
    if (t == 0) {
        float tot = 0.0f;
#pragma unroll
        for (int i = 0; i < 16; ++i) tot += red[i];
        out[0] = -tot / (float)BDIM;
    }
}

extern "C" void kernel_launch(void* const* d_in, const int* in_sizes, int n_in,
                              void* d_out, int out_size, void* d_ws, size_t ws_size,
                              hipStream_t stream)
{
    const int* labels = (const int*)d_in[0];
    const float* fa = (const float*)d_in[1];
    const float* fb = (const float*)d_in[2];
    float* out = (float*)d_out;

    // ws: a_n bf16 (8 MB) | b_n bf16 (8 MB) | num f32 (32 KB) | den f32 (32 KB)
    unsigned short* an = (unsigned short*)d_ws;
    unsigned short* bn = an + (size_t)BDIM * DDIM;
    float* num = (float*)(bn + (size_t)BDIM * DDIM);
    float* den = num + BDIM;

    hipMemsetAsync(num, 0, 2 * BDIM * sizeof(float), stream);  // ws is poisoned each call
    normalize_kernel<<<4096, 256, 0, stream>>>(fa, fb, an, bn);
    dim3 grid(32, 64);
    gemm_fused_kernel<<<grid, 256, 0, stream>>>(an, bn, labels, out + 1, num, den);
    loss_kernel<<<1, 1024, 0, stream>>>(num, den, out);
}